// Round 8
// baseline (88.840 us; speedup 1.0000x reference)
//
#include <hip/hip_runtime.h>
#include <cfloat>

// Problem constants (fixed by setup_inputs)
#define C_DIM   256
#define HW      1024
#define N_ROWS  32768
#define K_CODES 1024
#define ROWS    64            // rows per workgroup
#define NCHUNK  32            // chunks per sweep; wave-private chunk = 16 codes
#define WCHUNK_BYTES 8192     // 16 codes * 256 * 2B fp16
#define LISTCAP 256           // per-wave candidate list
#define DELTA   0.008f

#define OUT_ELEMS 8388608
#define LOSS_OFF  8388608
#define IDX_OFF   8388611

typedef _Float16 half8 __attribute__((ext_vector_type(8)));
typedef _Float16 f16x4 __attribute__((ext_vector_type(4)));
typedef float    f32x4 __attribute__((ext_vector_type(4)));

#define AS1 __attribute__((address_space(1)))
#define AS3 __attribute__((address_space(3)))

// dynamic LDS layout (bytes); ebuf region reused as qt[32][258] f32 (33024B) in the tail
#define OFF_EBUF  0                    // 4 waves * 2 bufs * 8192 = 65536
#define OFF_EN    65536                // 1024*4 = 4096
#define OFF_S32   69632                // 64*4
#define OFF_M1W   69888                // 2*64*4
#define OFF_THR   70400                // 64*4
#define OFF_RES   70656                // 64*8
#define OFF_FIDX  71168                // 64*4
#define OFF_LCNT  71424                // 64 (pad)
#define OFF_LMETA 71680                // 4*256*4 = 4096
#define SMEM_BYTES 75776               // x2 = 151552 <= 163840 -> 2 blocks/CU

#define QT_STRIDE 258

// min across the 16-lane row group (lanes sharing lane>>4)
#define DPP_MIN(x, ctrl) fminf((x), __int_as_float(__builtin_amdgcn_update_dpp(0, __float_as_int(x), (ctrl), 0xf, 0xf, true)))

// Kernel 1: codebook prep — fp32 norms (fp64-accurate) + fp16 copy, pre-swizzled.
// ws fp16 layout: byte = (k/32)*16384 + (k%32)*512 + ((c*2) ^ ((k&15)<<4) ^ ((k&1)<<8))
__global__ void prep_kernel(const float* __restrict__ cb, float* __restrict__ enorm,
                            char* __restrict__ cb16) {
    int k = blockIdx.x * 4 + (threadIdx.x >> 6);
    int lane = threadIdx.x & 63;
    float4 v = *(const float4*)(cb + k * C_DIM + lane * 4);
    double s = (double)v.x * v.x + (double)v.y * v.y + (double)v.z * v.z + (double)v.w * v.w;
    #pragma unroll
    for (int m = 1; m < 64; m <<= 1) s += __shfl_xor(s, m, 64);
    if (lane == 0) enorm[k] = (float)s;
    f16x4 h;
    h[0] = (_Float16)v.x; h[1] = (_Float16)v.y; h[2] = (_Float16)v.z; h[3] = (_Float16)v.w;
    int dst = ((k >> 5) << 14) + ((k & 31) << 9)
            + ((lane * 8) ^ ((k & 15) << 4) ^ ((k & 1) << 8));
    *(f16x4*)(cb16 + dst) = h;
}

// Kernel 2: two-phase fp16-MFMA prune, wave-private staging, ZERO in-loop barriers.
__global__ __launch_bounds__(256, 2) void vq_main(
    const float* __restrict__ x, const float* __restrict__ cb,
    const float* __restrict__ enorm_g, const char* __restrict__ cb16,
    float* __restrict__ out, float* __restrict__ idx_out, float* __restrict__ t2_out)
{
    extern __shared__ char smem[];
    float* qt      = (float*)(smem + OFF_EBUF);   // tail-phase alias
    float* en_lds  = (float*)(smem + OFF_EN);
    float* S32     = (float*)(smem + OFF_S32);
    float* m1w     = (float*)(smem + OFF_M1W);
    float* thr     = (float*)(smem + OFF_THR);
    unsigned long long* res = (unsigned long long*)(smem + OFF_RES);
    int*   fidx    = (int*)(smem + OFF_FIDX);
    int*   lcnt    = (int*)(smem + OFF_LCNT);
    unsigned int* lmeta = (unsigned int*)(smem + OFF_LMETA);

    const int t    = threadIdx.x;
    const int lane = t & 63;
    const int wv   = t >> 6;
    const int wr   = wv >> 1;          // row half: rows wr*32 .. wr*32+31
    const int wc   = wv & 1;           // code half within 32-code super-chunk
    const int l15  = lane & 15;
    const int l4   = lane >> 4;
    const int row0 = blockIdx.x * ROWS;
    const int b    = row0 >> 10;
    const int hw0  = row0 & 1023;
    const float* xb = x + b * (C_DIM * HW) + hw0;

    char* ebw = smem + OFF_EBUF + wv * (2 * WCHUNK_BYTES);   // wave-private 2x8KB
    const char* cbw = cb16 + (wc << 13);                     // this wave's code half

    // ---- issue wave-private staging for chunks 0,1 (lands under the A-build) ----
    #pragma unroll
    for (int c2 = 0; c2 < 2; c2++) {
        const char* src = cbw + (c2 << 14);
        char* dst = ebw + c2 * WCHUNK_BYTES;
        #pragma unroll
        for (int i = 0; i < 8; i++) {
            __builtin_amdgcn_global_load_lds((const AS1 unsigned int*)(src + i * 1024 + lane * 16),
                                             (AS3 unsigned int*)(dst + i * 1024), 16, 0, 0);
        }
    }

    // ---- stage enorm + reset counters ----
    *(float4*)&en_lds[t * 4] = *(const float4*)(enorm_g + t * 4);
    if (t < 4) lcnt[t] = 0;

    // ---- A fragments direct from global x (fp16, scaled by -2) + fp64 S32 ----
    half8 af[2][8];
    double s64[2] = {0.0, 0.0};
    #pragma unroll
    for (int rt = 0; rt < 2; rt++) {
        const float* xr = xb + wr * 32 + rt * 16 + l15;
        #pragma unroll
        for (int kk = 0; kk < 8; kk++) {
            float v[8];
            #pragma unroll
            for (int j = 0; j < 8; j++) v[j] = xr[(kk * 32 + l4 * 8 + j) * HW];
            #pragma unroll
            for (int j = 0; j < 8; j++) s64[rt] = fma((double)v[j], (double)v[j], s64[rt]);
            half8 h;
            #pragma unroll
            for (int j = 0; j < 8; j++) h[j] = (_Float16)(-2.0f * v[j]);
            af[rt][kk] = h;
        }
    }
    #pragma unroll
    for (int rt = 0; rt < 2; rt++) {
        s64[rt] += __shfl_xor(s64[rt], 16, 64);
        s64[rt] += __shfl_xor(s64[rt], 32, 64);
    }
    if (l4 == 0 && wc == 0) {
        S32[wr * 32 + l15]      = (float)s64[0];
        S32[wr * 32 + 16 + l15] = (float)s64[1];
    }
    __syncthreads();   // S32/en visible; chunks 0,1 landed (full drain, once)

    const int swzB = (l15 << 4) ^ ((l15 & 1) << 8);
    const int bofs = (l15 << 9);

    // ================= PHASE 1: min-only sweep (no barriers, no DPP) =================
    float m_loc[2][4];
    #pragma unroll
    for (int rt = 0; rt < 2; rt++)
        #pragma unroll
        for (int r2 = 0; r2 < 4; r2++) m_loc[rt][r2] = FLT_MAX;

    for (int ch = 0; ch < NCHUNK; ch++) {
        if (ch == NCHUNK - 1) { asm volatile("s_waitcnt vmcnt(0)" ::: "memory"); }
        else                  { asm volatile("s_waitcnt vmcnt(8)" ::: "memory"); }
        __builtin_amdgcn_sched_barrier(0);

        const char* ebc = ebw + (ch & 1) * WCHUNK_BYTES;
        half8 bf[8];
        #pragma unroll
        for (int kk = 0; kk < 8; kk++)
            bf[kk] = *(const half8*)(ebc + bofs + (((kk << 6) | (l4 << 4)) ^ swzB));
        asm volatile("s_waitcnt lgkmcnt(0)" ::: "memory");   // bf in regs; buffer dead
        __builtin_amdgcn_sched_barrier(0);

        if (ch + 2 < NCHUNK) {       // refill same buffer for ch+2
            const char* src = cbw + ((ch + 2) << 14);
            char* dst = ebw + (ch & 1) * WCHUNK_BYTES;
            #pragma unroll
            for (int i = 0; i < 8; i++) {
                __builtin_amdgcn_global_load_lds((const AS1 unsigned int*)(src + i * 1024 + lane * 16),
                                                 (AS3 unsigned int*)(dst + i * 1024), 16, 0, 0);
            }
        }

        const float en = en_lds[ch * 32 + wc * 16 + l15];
        f32x4 acc0 = {en, en, en, en};
        f32x4 acc1 = {en, en, en, en};
        #pragma unroll
        for (int kk = 0; kk < 8; kk++) {
            acc0 = __builtin_amdgcn_mfma_f32_16x16x32_f16(af[0][kk], bf[kk], acc0, 0, 0, 0);
            acc1 = __builtin_amdgcn_mfma_f32_16x16x32_f16(af[1][kk], bf[kk], acc1, 0, 0, 0);
        }
        #pragma unroll
        for (int r2 = 0; r2 < 4; r2++) {
            m_loc[0][r2] = fminf(m_loc[0][r2], acc0[r2]);
            m_loc[1][r2] = fminf(m_loc[1][r2], acc1[r2]);
        }
    }

    // ---- restage chunks 0,1 for phase 2 (latency hidden under the merge) ----
    #pragma unroll
    for (int c2 = 0; c2 < 2; c2++) {
        const char* src = cbw + (c2 << 14);
        char* dst = ebw + c2 * WCHUNK_BYTES;
        #pragma unroll
        for (int i = 0; i < 8; i++) {
            __builtin_amdgcn_global_load_lds((const AS1 unsigned int*)(src + i * 1024 + lane * 16),
                                             (AS3 unsigned int*)(dst + i * 1024), 16, 0, 0);
        }
    }

    // ---- one-time reduce: DPP over 16 lanes, then cross-wave merge -> thr ----
    #pragma unroll
    for (int rt = 0; rt < 2; rt++) {
        #pragma unroll
        for (int r2 = 0; r2 < 4; r2++) {
            float m = m_loc[rt][r2];
            m = DPP_MIN(m, 0xB1);
            m = DPP_MIN(m, 0x4E);
            m = DPP_MIN(m, 0x141);
            m = DPP_MIN(m, 0x140);   // min over this wave's 16 code-columns
            if (l15 == 0) m1w[wc * 64 + wr * 32 + rt * 16 + l4 * 4 + r2] = m;
        }
    }
    __syncthreads();
    if (t < 64) {
        thr[t] = fminf(m1w[t], m1w[64 + t]) + DELTA;   // true min over 1024 codes + delta
        res[t] = ~0ull;
    }
    __syncthreads();
    float thr_r[2][4];
    #pragma unroll
    for (int rt = 0; rt < 2; rt++)
        #pragma unroll
        for (int r2 = 0; r2 < 4; r2++)
            thr_r[rt][r2] = thr[wr * 32 + rt * 16 + l4 * 4 + r2];

    // ================= PHASE 2: collect sweep (rare pushes, no barriers) =================
    for (int ch = 0; ch < NCHUNK; ch++) {
        if (ch == NCHUNK - 1) { asm volatile("s_waitcnt vmcnt(0)" ::: "memory"); }
        else                  { asm volatile("s_waitcnt vmcnt(8)" ::: "memory"); }
        __builtin_amdgcn_sched_barrier(0);

        const char* ebc = ebw + (ch & 1) * WCHUNK_BYTES;
        half8 bf[8];
        #pragma unroll
        for (int kk = 0; kk < 8; kk++)
            bf[kk] = *(const half8*)(ebc + bofs + (((kk << 6) | (l4 << 4)) ^ swzB));
        asm volatile("s_waitcnt lgkmcnt(0)" ::: "memory");
        __builtin_amdgcn_sched_barrier(0);

        if (ch + 2 < NCHUNK) {
            const char* src = cbw + ((ch + 2) << 14);
            char* dst = ebw + (ch & 1) * WCHUNK_BYTES;
            #pragma unroll
            for (int i = 0; i < 8; i++) {
                __builtin_amdgcn_global_load_lds((const AS1 unsigned int*)(src + i * 1024 + lane * 16),
                                                 (AS3 unsigned int*)(dst + i * 1024), 16, 0, 0);
            }
        }

        const int codeG = ch * 32 + wc * 16 + l15;
        const float en = en_lds[codeG];
        f32x4 acc0 = {en, en, en, en};
        f32x4 acc1 = {en, en, en, en};
        #pragma unroll
        for (int kk = 0; kk < 8; kk++) {
            acc0 = __builtin_amdgcn_mfma_f32_16x16x32_f16(af[0][kk], bf[kk], acc0, 0, 0, 0);
            acc1 = __builtin_amdgcn_mfma_f32_16x16x32_f16(af[1][kk], bf[kk], acc1, 0, 0, 0);
        }
        bool h0[4], h1[4];
        bool any = false;
        #pragma unroll
        for (int r2 = 0; r2 < 4; r2++) {
            h0[r2] = acc0[r2] < thr_r[0][r2];
            h1[r2] = acc1[r2] < thr_r[1][r2];
            any = any || h0[r2] || h1[r2];
        }
        if (__ballot(any)) {
            #pragma unroll
            for (int r2 = 0; r2 < 4; r2++) {
                if (h0[r2]) {
                    int slot = atomicAdd(&lcnt[wv], 1);
                    if (slot < LISTCAP) {
                        int row_l = wr * 32 + l4 * 4 + r2;
                        lmeta[wv * LISTCAP + slot] = ((unsigned)row_l << 16) | (unsigned)codeG;
                    }
                }
                if (h1[r2]) {
                    int slot = atomicAdd(&lcnt[wv], 1);
                    if (slot < LISTCAP) {
                        int row_l = wr * 32 + 16 + l4 * 4 + r2;
                        lmeta[wv * LISTCAP + slot] = ((unsigned)row_l << 16) | (unsigned)codeG;
                    }
                }
            }
        }
    }

    // ---- rescore survivors: fp64 dot (z re-read from global) -> fp32 ref sim ----
    {
        int n = lcnt[wv]; if (n > LISTCAP) n = LISTCAP;
        for (int base = 0; base < n; base += 4) {
            int it = base + l4;
            if (it < n) {
                unsigned meta = lmeta[wv * LISTCAP + it];
                int row  = (int)(meta >> 16);
                int code = (int)(meta & 1023u);
                const float* xr = xb + row;            // element c at xr[c*HW]
                const float* er = cb + code * C_DIM;
                double acc = 0.0;
                #pragma unroll
                for (int s2 = 0; s2 < 16; s2++) {
                    int c = l15 + 16 * s2;
                    acc = fma((double)xr[(size_t)c * HW], (double)er[c], acc);
                }
                acc += __shfl_xor(acc, 1, 64);
                acc += __shfl_xor(acc, 2, 64);
                acc += __shfl_xor(acc, 4, 64);
                acc += __shfl_xor(acc, 8, 64);
                if (l15 == 0) {
                    float Mf = (float)acc;
                    float t2 = __fadd_rn(__fsub_rn(S32[row], __fmul_rn(2.0f, Mf)), en_lds[code]);
                    unsigned long long pk =
                        ((unsigned long long)__float_as_uint(t2) << 32) | (unsigned long long)(unsigned)code;
                    atomicMin(&res[row], pk);
                }
            }
        }
    }
    __syncthreads();

    if (t < 64) {
        unsigned long long v = res[t];
        int code = (int)(v & 1023u);
        fidx[t] = code;
        idx_out[row0 + t] = (float)code;
        t2_out[row0 + t] = __uint_as_float((unsigned)(v >> 32));
    }

    // ---- quantized output (NCHW) via LDS bounce: coalesced reads AND stores ----
    float* ob = out + b * (C_DIM * HW) + hw0;
    #pragma unroll
    for (int half = 0; half < 2; half++) {
        __syncthreads();   // fidx ready (first iter); prior half's stores done (second)
        for (int idx = t; idx < 32 * 64; idx += 256) {
            int r  = idx >> 6;         // 0..31
            int c4 = idx & 63;
            const float* er = cb + fidx[half * 32 + r] * C_DIM;
            *(float4*)&qt[r * QT_STRIDE + c4 * 4] = *(const float4*)(er + c4 * 4);
        }
        __syncthreads();
        int rr = t & 31;
        int cg = t >> 5;               // 0..7
        for (int cc = cg; cc < C_DIM; cc += 8) {
            ob[cc * HW + half * 32 + rr] = qt[rr * QT_STRIDE + cc];
        }
    }
}

// Kernel 3: deterministic loss reduction over per-row t2
__global__ void loss_kernel(const float* __restrict__ t2min, float* __restrict__ losses) {
    __shared__ double sh[256];
    int t = threadIdx.x;
    double a = 0.0;
    const int per = N_ROWS / 256;
    for (int i = t * per; i < t * per + per; i++) a += (double)t2min[i];
    sh[t] = a;
    __syncthreads();
    for (int s = 128; s > 0; s >>= 1) {
        if (t < s) sh[t] += sh[t + s];
        __syncthreads();
    }
    if (t == 0) {
        double M = sh[0] / (double)OUT_ELEMS;
        losses[0] = (float)(1.25 * M);   // quantizer_loss
        losses[1] = (float)(0.25 * M);   // e_latent_loss
        losses[2] = (float)(M);          // q_latent_loss
    }
}

extern "C" void kernel_launch(void* const* d_in, const int* in_sizes, int n_in,
                              void* d_out, int out_size, void* d_ws, size_t ws_size,
                              hipStream_t stream) {
    const float* x  = (const float*)d_in[0];
    const float* cb = (const float*)d_in[1];
    float* out     = (float*)d_out;
    float* losses  = out + LOSS_OFF;
    float* idx_out = out + IDX_OFF;

    char*  cb16     = (char*)d_ws;                               // 524288 B
    float* t2ws     = (float*)((char*)d_ws + 524288);            // 131072 B
    float* enorm_ws = (float*)((char*)d_ws + 524288 + 131072);   // 4096 B

    hipFuncSetAttribute(reinterpret_cast<const void*>(vq_main),
                        hipFuncAttributeMaxDynamicSharedMemorySize, SMEM_BYTES);

    prep_kernel<<<K_CODES / 4, 256, 0, stream>>>(cb, enorm_ws, cb16);
    vq_main<<<N_ROWS / ROWS, 256, SMEM_BYTES, stream>>>(x, cb, enorm_ws, cb16, out, idx_out, t2ws);
    loss_kernel<<<1, 256, 0, stream>>>(t2ws, losses);
}

// Round 9
// 74.802 us; speedup vs baseline: 1.1877x; 1.1877x over previous
//
#include <hip/hip_runtime.h>
#include <cfloat>

// Problem constants (fixed by setup_inputs)
#define C_DIM   256
#define HW      1024
#define N_ROWS  32768
#define K_CODES 1024
#define ROWS    64            // rows per workgroup
#define NCHUNK  32            // chunks per sweep; wave-private chunk = 16 codes
#define WCHUNK_BYTES 8192     // 16 codes * 256 * 2B fp16
#define LISTCAP 128           // per-wave candidate list (pushes ~ 8-24/wave)
#define DELTA   0.008f

#define OUT_ELEMS 8388608
#define LOSS_OFF  8388608
#define IDX_OFF   8388611

typedef _Float16 half8 __attribute__((ext_vector_type(8)));
typedef _Float16 f16x4 __attribute__((ext_vector_type(4)));
typedef float    f32x4 __attribute__((ext_vector_type(4)));

#define AS1 __attribute__((address_space(1)))
#define AS3 __attribute__((address_space(3)))

// dynamic LDS layout (bytes); ebuf region reused as qt[32][258] f32 (33024B) in the tail
#define OFF_EBUF  0                    // 4 waves * 2 bufs * 8192 = 65536
#define OFF_EN    65536                // 1024*4 = 4096
#define OFF_S32   69632                // 64*4
#define OFF_M1W   69888                // 2*64*4
#define OFF_THR   70400                // 64*4
#define OFF_RES   70656                // 64*8
#define OFF_FIDX  71168                // 64*4
#define OFF_LCNT  71424                // 64 (pad to 71680)
#define OFF_LMETA 71680                // 4*128*4 = 2048
#define SMEM_BYTES 73728               // x2 = 147456 <= 163840 -> 2 blocks/CU

#define QT_STRIDE 258

// min across the 16-lane row group (lanes sharing lane>>4)
#define DPP_MIN(x, ctrl) fminf((x), __int_as_float(__builtin_amdgcn_update_dpp(0, __float_as_int(x), (ctrl), 0xf, 0xf, true)))

// Kernel 1: codebook prep — fp32 norms (fp64-accurate) + fp16 copy, pre-swizzled.
// ws fp16 layout: byte = (k/32)*16384 + (k%32)*512 + ((c*2) ^ ((k&15)<<4) ^ ((k&1)<<8))
__global__ void prep_kernel(const float* __restrict__ cb, float* __restrict__ enorm,
                            char* __restrict__ cb16) {
    int k = blockIdx.x * 4 + (threadIdx.x >> 6);
    int lane = threadIdx.x & 63;
    float4 v = *(const float4*)(cb + k * C_DIM + lane * 4);
    double s = (double)v.x * v.x + (double)v.y * v.y + (double)v.z * v.z + (double)v.w * v.w;
    #pragma unroll
    for (int m = 1; m < 64; m <<= 1) s += __shfl_xor(s, m, 64);
    if (lane == 0) enorm[k] = (float)s;
    f16x4 h;
    h[0] = (_Float16)v.x; h[1] = (_Float16)v.y; h[2] = (_Float16)v.z; h[3] = (_Float16)v.w;
    int dst = ((k >> 5) << 14) + ((k & 31) << 9)
            + ((lane * 8) ^ ((k & 15) << 4) ^ ((k & 1) << 8));
    *(f16x4*)(cb16 + dst) = h;
}

// Kernel 2: SINGLE-sweep fp16-MFMA prune with in-register top-2 per lane-slot,
// wave-private staging, zero in-loop barriers; exact fp32-sim rescore.
__global__ __launch_bounds__(256, 2) void vq_main(
    const float* __restrict__ x, const float* __restrict__ cb,
    const float* __restrict__ enorm_g, const char* __restrict__ cb16,
    float* __restrict__ out, float* __restrict__ idx_out, float* __restrict__ t2_out)
{
    extern __shared__ char smem[];
    float* qt      = (float*)(smem + OFF_EBUF);   // tail-phase alias
    float* en_lds  = (float*)(smem + OFF_EN);
    float* S32     = (float*)(smem + OFF_S32);
    float* m1w     = (float*)(smem + OFF_M1W);
    float* thr     = (float*)(smem + OFF_THR);
    unsigned long long* res = (unsigned long long*)(smem + OFF_RES);
    int*   fidx    = (int*)(smem + OFF_FIDX);
    int*   lcnt    = (int*)(smem + OFF_LCNT);
    unsigned int* lmeta = (unsigned int*)(smem + OFF_LMETA);

    const int t    = threadIdx.x;
    const int lane = t & 63;
    const int wv   = t >> 6;
    const int wr   = wv >> 1;          // row half: rows wr*32 .. wr*32+31
    const int wc   = wv & 1;           // code half within 32-code super-chunk
    const int l15  = lane & 15;
    const int l4   = lane >> 4;
    const int row0 = blockIdx.x * ROWS;
    const int b    = row0 >> 10;
    const int hw0  = row0 & 1023;
    const float* xb = x + b * (C_DIM * HW) + hw0;

    char* ebw = smem + OFF_EBUF + wv * (2 * WCHUNK_BYTES);   // wave-private 2x8KB
    const char* cbw = cb16 + (wc << 13);                     // this wave's code half

    // ---- issue wave-private staging for chunks 0,1 (lands under the A-build) ----
    #pragma unroll
    for (int c2 = 0; c2 < 2; c2++) {
        const char* src = cbw + (c2 << 14);
        char* dst = ebw + c2 * WCHUNK_BYTES;
        #pragma unroll
        for (int i = 0; i < 8; i++) {
            __builtin_amdgcn_global_load_lds((const AS1 unsigned int*)(src + i * 1024 + lane * 16),
                                             (AS3 unsigned int*)(dst + i * 1024), 16, 0, 0);
        }
    }

    // ---- stage enorm + reset counters ----
    *(float4*)&en_lds[t * 4] = *(const float4*)(enorm_g + t * 4);
    if (t < 4) lcnt[t] = 0;

    // ---- A fragments direct from global x (fp16, scaled by -2) + fp64 S32 ----
    half8 af[2][8];
    double s64[2] = {0.0, 0.0};
    #pragma unroll
    for (int rt = 0; rt < 2; rt++) {
        const float* xr = xb + wr * 32 + rt * 16 + l15;
        #pragma unroll
        for (int kk = 0; kk < 8; kk++) {
            float v[8];
            #pragma unroll
            for (int j = 0; j < 8; j++) v[j] = xr[(kk * 32 + l4 * 8 + j) * HW];
            #pragma unroll
            for (int j = 0; j < 8; j++) s64[rt] = fma((double)v[j], (double)v[j], s64[rt]);
            half8 h;
            #pragma unroll
            for (int j = 0; j < 8; j++) h[j] = (_Float16)(-2.0f * v[j]);
            af[rt][kk] = h;
        }
    }
    #pragma unroll
    for (int rt = 0; rt < 2; rt++) {
        s64[rt] += __shfl_xor(s64[rt], 16, 64);
        s64[rt] += __shfl_xor(s64[rt], 32, 64);
    }
    if (l4 == 0 && wc == 0) {
        S32[wr * 32 + l15]      = (float)s64[0];
        S32[wr * 32 + 16 + l15] = (float)s64[1];
    }
    __syncthreads();   // S32/en visible; chunks 0,1 landed (full drain, once)

    const int swzB = (l15 << 4) ^ ((l15 & 1) << 8);
    const int bofs = (l15 << 9);

    // ====== SINGLE SWEEP: MFMA + lane-local top-2 per slot (no barriers) ======
    float s1v[2][4], s2v[2][4];
    int   c1v[2][4], c2v[2][4];
    #pragma unroll
    for (int rt = 0; rt < 2; rt++)
        #pragma unroll
        for (int r2 = 0; r2 < 4; r2++) {
            s1v[rt][r2] = FLT_MAX; s2v[rt][r2] = FLT_MAX;
            c1v[rt][r2] = 0;       c2v[rt][r2] = 0;
        }

    for (int ch = 0; ch < NCHUNK; ch++) {
        if (ch == NCHUNK - 1) { asm volatile("s_waitcnt vmcnt(0)" ::: "memory"); }
        else                  { asm volatile("s_waitcnt vmcnt(8)" ::: "memory"); }
        __builtin_amdgcn_sched_barrier(0);

        const char* ebc = ebw + (ch & 1) * WCHUNK_BYTES;
        half8 bf[8];
        #pragma unroll
        for (int kk = 0; kk < 8; kk++)
            bf[kk] = *(const half8*)(ebc + bofs + (((kk << 6) | (l4 << 4)) ^ swzB));
        asm volatile("s_waitcnt lgkmcnt(0)" ::: "memory");   // bf in regs; buffer dead
        __builtin_amdgcn_sched_barrier(0);

        if (ch + 2 < NCHUNK) {       // refill same buffer for ch+2
            const char* src = cbw + ((ch + 2) << 14);
            char* dst = ebw + (ch & 1) * WCHUNK_BYTES;
            #pragma unroll
            for (int i = 0; i < 8; i++) {
                __builtin_amdgcn_global_load_lds((const AS1 unsigned int*)(src + i * 1024 + lane * 16),
                                                 (AS3 unsigned int*)(dst + i * 1024), 16, 0, 0);
            }
        }

        const float en = en_lds[ch * 32 + wc * 16 + l15];
        f32x4 acc0 = {en, en, en, en};
        f32x4 acc1 = {en, en, en, en};
        #pragma unroll
        for (int kk = 0; kk < 8; kk++) {
            acc0 = __builtin_amdgcn_mfma_f32_16x16x32_f16(af[0][kk], bf[kk], acc0, 0, 0, 0);
            acc1 = __builtin_amdgcn_mfma_f32_16x16x32_f16(af[1][kk], bf[kk], acc1, 0, 0, 0);
        }
        // lane-local top-2 update per slot (no cross-lane ops)
        #pragma unroll
        for (int r2 = 0; r2 < 4; r2++) {
            float s0 = acc0[r2];
            if (s0 < s1v[0][r2]) {
                s2v[0][r2] = s1v[0][r2]; c2v[0][r2] = c1v[0][r2];
                s1v[0][r2] = s0;         c1v[0][r2] = ch;
            } else if (s0 < s2v[0][r2]) {
                s2v[0][r2] = s0;         c2v[0][r2] = ch;
            }
            float s1 = acc1[r2];
            if (s1 < s1v[1][r2]) {
                s2v[1][r2] = s1v[1][r2]; c2v[1][r2] = c1v[1][r2];
                s1v[1][r2] = s1;         c1v[1][r2] = ch;
            } else if (s1 < s2v[1][r2]) {
                s2v[1][r2] = s1;         c2v[1][r2] = ch;
            }
        }
    }

    // ---- one-time reduce: DPP over 16 lanes -> per-row wave min; cross-wave merge ----
    #pragma unroll
    for (int rt = 0; rt < 2; rt++) {
        #pragma unroll
        for (int r2 = 0; r2 < 4; r2++) {
            float m = s1v[rt][r2];
            m = DPP_MIN(m, 0xB1);
            m = DPP_MIN(m, 0x4E);
            m = DPP_MIN(m, 0x141);
            m = DPP_MIN(m, 0x140);   // min over this wave's 16 code-columns
            if (l15 == 0) m1w[wc * 64 + wr * 32 + rt * 16 + l4 * 4 + r2] = m;
        }
    }
    __syncthreads();
    if (t < 64) {
        thr[t] = fminf(m1w[t], m1w[64 + t]) + DELTA;   // true min over 1024 codes + delta
        res[t] = ~0ull;
    }
    __syncthreads();

    // ---- push candidates from register top-2 (once, tiny) ----
    #pragma unroll
    for (int rt = 0; rt < 2; rt++) {
        #pragma unroll
        for (int r2 = 0; r2 < 4; r2++) {
            int row_l = wr * 32 + rt * 16 + l4 * 4 + r2;
            float tr = thr[row_l];
            if (s1v[rt][r2] < tr) {
                int code = c1v[rt][r2] * 32 + wc * 16 + l15;
                int slot = atomicAdd(&lcnt[wv], 1);
                if (slot < LISTCAP)
                    lmeta[wv * LISTCAP + slot] = ((unsigned)row_l << 16) | (unsigned)code;
            }
            if (s2v[rt][r2] < tr) {
                int code = c2v[rt][r2] * 32 + wc * 16 + l15;
                int slot = atomicAdd(&lcnt[wv], 1);
                if (slot < LISTCAP)
                    lmeta[wv * LISTCAP + slot] = ((unsigned)row_l << 16) | (unsigned)code;
            }
        }
    }
    __syncthreads();

    // ---- rescore survivors: fp64 dot (z re-read from global) -> fp32 ref sim ----
    {
        int n = lcnt[wv]; if (n > LISTCAP) n = LISTCAP;
        for (int base = 0; base < n; base += 4) {
            int it = base + l4;
            if (it < n) {
                unsigned meta = lmeta[wv * LISTCAP + it];
                int row  = (int)(meta >> 16);
                int code = (int)(meta & 1023u);
                const float* xr = xb + row;            // element c at xr[c*HW]
                const float* er = cb + code * C_DIM;
                double acc = 0.0;
                #pragma unroll
                for (int s2 = 0; s2 < 16; s2++) {
                    int c = l15 + 16 * s2;
                    acc = fma((double)xr[(size_t)c * HW], (double)er[c], acc);
                }
                acc += __shfl_xor(acc, 1, 64);
                acc += __shfl_xor(acc, 2, 64);
                acc += __shfl_xor(acc, 4, 64);
                acc += __shfl_xor(acc, 8, 64);
                if (l15 == 0) {
                    float Mf = (float)acc;
                    float t2 = __fadd_rn(__fsub_rn(S32[row], __fmul_rn(2.0f, Mf)), en_lds[code]);
                    unsigned long long pk =
                        ((unsigned long long)__float_as_uint(t2) << 32) | (unsigned long long)(unsigned)code;
                    atomicMin(&res[row], pk);
                }
            }
        }
    }
    __syncthreads();

    if (t < 64) {
        unsigned long long v = res[t];
        int code = (int)(v & 1023u);
        fidx[t] = code;
        idx_out[row0 + t] = (float)code;
        t2_out[row0 + t] = __uint_as_float((unsigned)(v >> 32));
    }

    // ---- quantized output (NCHW) via LDS bounce: coalesced reads AND stores ----
    float* ob = out + b * (C_DIM * HW) + hw0;
    #pragma unroll
    for (int half = 0; half < 2; half++) {
        __syncthreads();   // fidx ready (first iter); prior half's stores done (second)
        for (int idx = t; idx < 32 * 64; idx += 256) {
            int r  = idx >> 6;         // 0..31
            int c4 = idx & 63;
            const float* er = cb + fidx[half * 32 + r] * C_DIM;
            *(float4*)&qt[r * QT_STRIDE + c4 * 4] = *(const float4*)(er + c4 * 4);
        }
        __syncthreads();
        int rr = t & 31;
        int cg = t >> 5;               // 0..7
        for (int cc = cg; cc < C_DIM; cc += 8) {
            ob[cc * HW + half * 32 + rr] = qt[rr * QT_STRIDE + cc];
        }
    }
}

// Kernel 3: deterministic loss reduction over per-row t2
__global__ void loss_kernel(const float* __restrict__ t2min, float* __restrict__ losses) {
    __shared__ double sh[256];
    int t = threadIdx.x;
    double a = 0.0;
    const int per = N_ROWS / 256;
    for (int i = t * per; i < t * per + per; i++) a += (double)t2min[i];
    sh[t] = a;
    __syncthreads();
    for (int s = 128; s > 0; s >>= 1) {
        if (t < s) sh[t] += sh[t + s];
        __syncthreads();
    }
    if (t == 0) {
        double M = sh[0] / (double)OUT_ELEMS;
        losses[0] = (float)(1.25 * M);   // quantizer_loss
        losses[1] = (float)(0.25 * M);   // e_latent_loss
        losses[2] = (float)(M);          // q_latent_loss
    }
}

extern "C" void kernel_launch(void* const* d_in, const int* in_sizes, int n_in,
                              void* d_out, int out_size, void* d_ws, size_t ws_size,
                              hipStream_t stream) {
    const float* x  = (const float*)d_in[0];
    const float* cb = (const float*)d_in[1];
    float* out     = (float*)d_out;
    float* losses  = out + LOSS_OFF;
    float* idx_out = out + IDX_OFF;

    char*  cb16     = (char*)d_ws;                               // 524288 B
    float* t2ws     = (float*)((char*)d_ws + 524288);            // 131072 B
    float* enorm_ws = (float*)((char*)d_ws + 524288 + 131072);   // 4096 B

    hipFuncSetAttribute(reinterpret_cast<const void*>(vq_main),
                        hipFuncAttributeMaxDynamicSharedMemorySize, SMEM_BYTES);

    prep_kernel<<<K_CODES / 4, 256, 0, stream>>>(cb, enorm_ws, cb16);
    vq_main<<<N_ROWS / ROWS, 256, SMEM_BYTES, stream>>>(x, cb, enorm_ws, cb16, out, idx_out, t2ws);
    loss_kernel<<<1, 256, 0, stream>>>(t2ws, losses);
}